// Round 5
// baseline (370.169 us; speedup 1.0000x reference)
//
#include <hip/hip_runtime.h>
#include <math.h>

#define VIF_EPS       1e-10f
#define SIGMA_NSQ     2.0f
#define SIGMA_MAX_INV (4.0f / (255.0f * 255.0f))
#define GAIN_LIMIT    100.0f

// jnp.pad mode='reflect' (no edge duplication). Overshoot < dim, single reflection suffices.
__device__ __forceinline__ int reflect_idx(int i, int n) {
    i = (i < 0) ? -i : i;
    i = (i >= n) ? (2 * n - 2 - i) : i;
    return i;
}

// Reference: sigma=N/5; g=exp(-x^2/(2 sigma^2)); win=outer(g,g)/sum -> separable gn = g/sum(g).
template <int N>
__device__ __forceinline__ void compute_weights(float* wts) {
    if (threadIdx.x == 0) {
        const float sigma = (float)N / 5.0f;
        const float denom = 2.0f * sigma * sigma;
        float s = 0.0f;
        for (int i = 0; i < N; ++i) {
            float x = (float)i - (float)(N - 1) * 0.5f;
            float g = expf(-(x * x) / denom);
            wts[i] = g;
            s += g;
        }
        for (int i = 0; i < N; ++i) wts[i] = wts[i] / s;
    }
}

// Output tile width: 128 staged columns minus halo, rounded down to multiple of 8
// (phase 2 uses 8 outputs/thread).
constexpr int tile_w(int N) { return (128 - (N - 1)) & ~7; }

// Shared-memory footprints (host mirrors for dynamic LDS sizing).
constexpr int align16(int x) { return (x + 15) & ~15; }
constexpr int stats_smem(int N) { return align16(N * 4) + 5 * 8 * 132 * 4 + 32; }
constexpr int down_smem(int N) {
    int IH = 14 + N, IW = 62 + N, IWP = ((IW + 3) / 4) * 4;
    return align16(N * 4) + align16(2 * IH * IWP * 4) + 2 * IH * 32 * 4;
}
constexpr int max_i(int a, int b) { return a > b ? a : b; }

// ---------------- stats body (vertical-first separable VIF) ----------------
// bx is the flattened block id, Y-MAJOR (ytile = bx % sy) so vertical-halo
// re-reads hit L2 from temporally adjacent blocks.
// Phase 1: 256 threads = 128 cols x 2 row-groups; coalesced global column loads,
//   5 product channels + N-tap vertical conv in registers (4 rows/thread); only the
//   vertical results go to LDS: v[5][8][132].
// Phase 2: 8 consecutive x-outputs/thread (24-float register window via float4 LDS
//   reads), N-tap horizontal conv + VIF math, block reduction -> double2 partial.
// NOTE: plain __launch_bounds__(256) — a min-waves bound forced VGPR=48 in round 3
// and generated ~930 MB/dispatch of scratch spill traffic.
template <int N>
__device__ __forceinline__ void stats_body(
    char* smem, const float* __restrict__ refp, const float* __restrict__ distp,
    int h, int w, float shift, double2* __restrict__ partial,
    int sy, int sx, int bx, int b) {
    constexpr int P   = (N - 1) / 2;
    constexpr int VC  = 128;
    constexpr int TW  = tile_w(N);
    constexpr int TH  = 8;
    constexpr int Q   = 4;                 // rows/thread, phase 1
    constexpr int LR  = Q + 2 * P;
    constexpr int VCP = VC + 4;            // 132: padded row stride
    constexpr int XG8 = TW / 8;            // x-groups of 8, phase 2
    constexpr int F4  = (N + 7 + 3) / 4;   // float4s covering N+7 floats

    float* wts  = (float*)smem;
    float* v    = (float*)(smem + align16(N * 4));   // 5*TH*VCP floats
    float* rsum = v + 5 * TH * VCP;                  // 8 floats

    const int tid = threadIdx.x;
    const int ytile = bx % sy;
    const int xtile = bx / sy;
    const int x0 = xtile * TW;
    const int y0 = ytile * TH;

    compute_weights<N>(wts);
    __syncthreads();

    float wr[N];
#pragma unroll
    for (int j = 0; j < N; ++j) wr[j] = wts[j];

    // ---- Phase 1: vertical conv from global ----
    {
        const int c = tid & (VC - 1);
        const int g = tid >> 7;            // 0..1
        const int gx = reflect_idx(x0 + c - P, w);
        const float* rb = refp  + (size_t)b * h * w + gx;
        const float* db = distp + (size_t)b * h * w + gx;

        float acc[5][Q];
#pragma unroll
        for (int ch = 0; ch < 5; ++ch)
#pragma unroll
            for (int q = 0; q < Q; ++q) acc[ch][q] = 0.f;

#pragma unroll
        for (int i = 0; i < LR; ++i) {
            int gy = reflect_idx(y0 + g * Q - P + i, h);
            float r = rb[(size_t)gy * w] - shift;
            float d = db[(size_t)gy * w] - shift;
            float p0 = r, p1 = d, p2 = r * r, p3 = d * d, p4 = r * d;
#pragma unroll
            for (int q = 0; q < Q; ++q) {
                int j = i - q;
                if (j >= 0 && j < N) {
                    float wj = wr[j];
                    acc[0][q] += wj * p0;
                    acc[1][q] += wj * p1;
                    acc[2][q] += wj * p2;
                    acc[3][q] += wj * p3;
                    acc[4][q] += wj * p4;
                }
            }
        }
#pragma unroll
        for (int ch = 0; ch < 5; ++ch)
#pragma unroll
            for (int q = 0; q < Q; ++q)
                v[(ch * TH + g * Q + q) * VCP + c] = acc[ch][q];
    }
    __syncthreads();

    // ---- Phase 2: horizontal conv + VIF math (8 outputs/thread) ----
    float num_v = 0.f, den_v = 0.f;
    {
        const int xg  = tid % XG8;
        const int row = tid / XG8;
        if (row < TH) {
            float mu[5][8];
#pragma unroll
            for (int ch = 0; ch < 5; ++ch) {
                float win[F4 * 4];
                const float4* s4 = (const float4*)&v[(ch * TH + row) * VCP + xg * 8];
#pragma unroll
                for (int f = 0; f < F4; ++f) {
                    float4 t = s4[f];
                    win[4 * f + 0] = t.x; win[4 * f + 1] = t.y;
                    win[4 * f + 2] = t.z; win[4 * f + 3] = t.w;
                }
#pragma unroll
                for (int q = 0; q < 8; ++q) {
                    float a = 0.f;
#pragma unroll
                    for (int j = 0; j < N; ++j) a += wr[j] * win[q + j];
                    mu[ch][q] = a;
                }
            }
            const int gy = y0 + row;
#pragma unroll
            for (int q = 0; q < 8; ++q) {
                int gx = x0 + xg * 8 + q;
                if (gx < w && gy < h) {
                    float mu1 = mu[0][q], mu2 = mu[1][q];
                    float s1  = fmaxf(0.f, mu[2][q] - mu1 * mu1);
                    float s2  = fmaxf(0.f, mu[3][q] - mu2 * mu2);
                    float s12 = mu[4][q] - mu1 * mu2;

                    float g  = s12 / (s1 + VIF_EPS);
                    float sv = s2 - g * s12;
                    if (s1 < VIF_EPS) { g = 0.f; sv = s2; s1 = 0.f; }
                    if (s2 < VIF_EPS) { g = 0.f; sv = 0.f; }
                    if (g  < 0.f)     { sv = s2; g = 0.f; }
                    if (sv <= VIF_EPS) sv = VIF_EPS;
                    g = fminf(g, GAIN_LIMIT);

                    float num_ar = __log2f(1.f + g * g * s1 / (sv + SIGMA_NSQ));
                    float den_ar = __log2f(1.f + s1 / SIGMA_NSQ);
                    if (s12 < 0.f) num_ar = 0.f;
                    if (s1 < SIGMA_NSQ) { num_ar = 1.f - s2 * SIGMA_MAX_INV; den_ar = 1.f; }
                    num_v += num_ar;
                    den_v += den_ar;
                }
            }
        }
    }

    // Block reduction: wave shuffle then cross-wave via LDS.
#pragma unroll
    for (int off = 32; off > 0; off >>= 1) {
        num_v += __shfl_down(num_v, off);
        den_v += __shfl_down(den_v, off);
    }
    const int wid = tid >> 6, lane = tid & 63;
    if (lane == 0) { rsum[wid] = num_v; rsum[4 + wid] = den_v; }
    __syncthreads();
    if (tid == 0) {
        float ns = rsum[0] + rsum[1] + rsum[2] + rsum[3];
        float ds = rsum[4] + rsum[5] + rsum[6] + rsum[7];
        partial[(size_t)b * (sy * sx) + bx] = make_double2((double)ns, (double)ds);
    }
}

// ---------------- downsample body (separable stride-2, both images) ----------------
template <int N>
__device__ __forceinline__ void down_body(
    char* smem, const float* __restrict__ rin, const float* __restrict__ din,
    float* __restrict__ rout, float* __restrict__ dout,
    int h, int w, int h2, int w2, float shift, int dgx, int bx, int b) {
    constexpr int P   = (N - 1) / 2;
    constexpr int TOX = 32, TOY = 8;
    constexpr int IH  = 2 * (TOY - 1) + N;
    constexpr int IW  = 2 * (TOX - 1) + N;
    constexpr int IWP = ((IW + 3) / 4) * 4;
    constexpr int F4  = (N + 10) / 4;
    constexpr int NG  = 2 * IH * (TOX / 4);

    float* wts = (float*)smem;
    float* lin = (float*)(smem + align16(N * 4));              // 2*IH*IWP floats
    float* hd  = (float*)(smem + align16(N * 4) + align16(2 * IH * IWP * 4));  // 2*IH*32

    compute_weights<N>(wts);

    const int tid = threadIdx.x;
    const int xt  = bx % dgx;
    const int yt  = bx / dgx;
    const int x0  = xt * TOX;
    const int y0  = yt * TOY;

    const float* src0 = rin + (size_t)b * h * w;
    const float* src1 = din + (size_t)b * h * w;

    __syncthreads();  // wts visible

    for (int idx = tid; idx < 2 * IH * IWP; idx += 256) {
        int img = idx / (IH * IWP);
        int rem = idx - img * IH * IWP;
        int r   = rem / IWP;
        int cx  = rem - r * IWP;
        int gy  = reflect_idx(2 * y0 - P + r, h);
        int gx  = reflect_idx(2 * x0 - P + cx, w);
        const float* src = img ? src1 : src0;
        lin[idx] = src[(size_t)gy * w + gx] - shift;
    }
    __syncthreads();

    for (int g = tid; g < NG; g += 256) {
        int img = g / (IH * 8);
        int rem = g - img * IH * 8;
        int r   = rem >> 3;
        int xg  = (rem & 7) * 4;
        float win[F4 * 4];
        const float4* src4 = (const float4*)&lin[(img * IH + r) * IWP + 2 * xg];
#pragma unroll
        for (int f = 0; f < F4; ++f) {
            float4 t = src4[f];
            win[4 * f + 0] = t.x; win[4 * f + 1] = t.y;
            win[4 * f + 2] = t.z; win[4 * f + 3] = t.w;
        }
#pragma unroll
        for (int q = 0; q < 4; ++q) {
            float a = 0.f;
#pragma unroll
            for (int j = 0; j < N; ++j) a += wts[j] * win[2 * q + j];
            hd[(img * IH + r) * TOX + xg + q] = a;
        }
    }
    __syncthreads();

    const int img = tid >> 7;
    const int rem = tid & 127;
    const int tx  = rem & 31;
    const int yg  = (rem >> 5) * 2;
    float* outp = (img ? dout : rout) + (size_t)b * h2 * w2;
#pragma unroll
    for (int q = 0; q < 2; ++q) {
        int yo = yg + q;
        int gy = y0 + yo, gx = x0 + tx;
        if (gy < h2 && gx < w2) {
            float a = 0.f;
#pragma unroll
            for (int j = 0; j < N; ++j) a += wts[j] * hd[(img * IH + 2 * yo + j) * TOX + tx];
            outp[(size_t)gy * w2 + gx] = a;
        }
    }
}

// ---------------- fused kernels ----------------
// Blocks [0, nStats) run stats<NS>; blocks [nStats, ...) run down<ND>.
// The two tasks are independent (stats reads level-i; down writes level-(i+1)).
template <int NS, int ND>
__global__ __launch_bounds__(256) void fused_kernel(
    const float* __restrict__ sref, const float* __restrict__ sdist,
    int sh, int sw, float sshift, double2* __restrict__ partial, int sy, int sx,
    const float* __restrict__ drin, const float* __restrict__ ddin,
    float* __restrict__ drout, float* __restrict__ ddout,
    int dh, int dw, int dh2, int dw2, float dshift, int dgx,
    int nStats) {
    extern __shared__ char smem[];
    const int bx = blockIdx.x;
    const int b  = blockIdx.z;
    if (bx < nStats)
        stats_body<NS>(smem, sref, sdist, sh, sw, sshift, partial, sy, sx, bx, b);
    else
        down_body<ND>(smem, drin, ddin, drout, ddout, dh, dw, dh2, dw2, dshift, dgx,
                      bx - nStats, b);
}

template <int N>
__global__ __launch_bounds__(256) void stats_only_kernel(
    const float* __restrict__ refp, const float* __restrict__ distp,
    int h, int w, float shift, double2* __restrict__ partial, int sy, int sx) {
    extern __shared__ char smem[];
    stats_body<N>(smem, refp, distp, h, w, shift, partial, sy, sx, blockIdx.x, blockIdx.z);
}

// 16 blocks: one per (batch, scale). Sums double2 partials, writes num/den to out.
__global__ __launch_bounds__(256) void reduce_kernel(
    const double2* __restrict__ part, float* __restrict__ out,
    int4 bases, int4 counts) {
    __shared__ double sn[4], sd[4];
    const int s = blockIdx.x & 3;
    const int b = blockIdx.x >> 2;
    const int base = (&bases.x)[s];
    const int cnt  = (&counts.x)[s];
    const double2* p = part + base + (size_t)b * cnt;

    double ns = 0.0, ds = 0.0;
    for (int i = threadIdx.x; i < cnt; i += 256) {
        double2 v = p[i];
        ns += v.x;
        ds += v.y;
    }
#pragma unroll
    for (int off = 32; off > 0; off >>= 1) {
        ns += __shfl_down(ns, off);
        ds += __shfl_down(ds, off);
    }
    const int wid = threadIdx.x >> 6, lane = threadIdx.x & 63;
    if (lane == 0) { sn[wid] = ns; sd[wid] = ds; }
    __syncthreads();
    if (threadIdx.x == 0) {
        double Nv = sn[0] + sn[1] + sn[2] + sn[3];
        double Dv = sd[0] + sd[1] + sd[2] + sd[3];
        out[b * 4 + s] = (float)(Nv / Dv);
    }
}

extern "C" void kernel_launch(void* const* d_in, const int* in_sizes, int n_in,
                              void* d_out, int out_size, void* d_ws, size_t ws_size,
                              hipStream_t stream) {
    const float* ref  = (const float*)d_in[0];
    const float* dist = (const float*)d_in[1];
    float* out = (float*)d_out;

    const int B = 4;
    const int H0 = 1080, W0 = 1920;
    const int H1 = 540,  W1 = 960;
    const int H2 = 270,  W2 = 480;
    const int H3 = 135,  W3 = 240;

    char*  ws  = (char*)d_ws;
    size_t off = 0;
    auto alloc = [&](size_t bytes) -> void* {
        void* p = ws + off;
        off += (bytes + 255) & ~(size_t)255;
        return p;
    };
    float* ref1  = (float*)alloc((size_t)B * H1 * W1 * 4);
    float* dist1 = (float*)alloc((size_t)B * H1 * W1 * 4);
    float* ref2  = (float*)alloc((size_t)B * H2 * W2 * 4);
    float* dist2 = (float*)alloc((size_t)B * H2 * W2 * 4);
    float* ref3  = (float*)alloc((size_t)B * H3 * W3 * 4);
    float* dist3 = (float*)alloc((size_t)B * H3 * W3 * 4);

    // Stats grids (tile = tile_w(N) x 8), flattened y-major.
    const int sx0 = (W0 + tile_w(17) - 1) / tile_w(17), sy0 = (H0 + 7) / 8;  // 18 x 135
    const int sx1 = (W1 + tile_w(9)  - 1) / tile_w(9),  sy1 = (H1 + 7) / 8;  // 8 x 68
    const int sx2 = (W2 + tile_w(5)  - 1) / tile_w(5),  sy2 = (H2 + 7) / 8;  // 4 x 34
    const int sx3 = (W3 + tile_w(3)  - 1) / tile_w(3),  sy3 = (H3 + 7) / 8;  // 2 x 17
    const int n0 = sx0 * sy0, n1 = sx1 * sy1, n2 = sx2 * sy2, n3 = sx3 * sy3;

    // Down grids (32x8 output tiles), flattened x-fastest.
    const int dgx1 = (W1 + 31) / 32, dgy1 = (H1 + 7) / 8, nD1 = dgx1 * dgy1;
    const int dgx2 = (W2 + 31) / 32, dgy2 = (H2 + 7) / 8, nD2 = dgx2 * dgy2;
    const int dgx3 = (W3 + 31) / 32, dgy3 = (H3 + 7) / 8, nD3 = dgx3 * dgy3;

    double2* part = (double2*)alloc((size_t)B * (n0 + n1 + n2 + n3) * sizeof(double2));
    double2* p0 = part;
    double2* p1 = p0 + (size_t)B * n0;
    double2* p2 = p1 + (size_t)B * n1;
    double2* p3 = p2 + (size_t)B * n2;

    dim3 blk(256);

    // K1: stats<17>(level0) + down<9>(level0 -> level1)
    {
        constexpr int smemB = max_i(stats_smem(17), down_smem(9));
        fused_kernel<17, 9><<<dim3(n0 + nD1, 1, B), blk, smemB, stream>>>(
            ref, dist, H0, W0, 128.0f, p0, sy0, sx0,
            ref, dist, ref1, dist1, H0, W0, H1, W1, 128.0f, dgx1, n0);
    }
    // K2: stats<9>(level1) + down<5>(level1 -> level2)
    {
        constexpr int smemB = max_i(stats_smem(9), down_smem(5));
        fused_kernel<9, 5><<<dim3(n1 + nD2, 1, B), blk, smemB, stream>>>(
            ref1, dist1, H1, W1, 0.0f, p1, sy1, sx1,
            ref1, dist1, ref2, dist2, H1, W1, H2, W2, 0.0f, dgx2, n1);
    }
    // K3: stats<5>(level2) + down<3>(level2 -> level3)
    {
        constexpr int smemB = max_i(stats_smem(5), down_smem(3));
        fused_kernel<5, 3><<<dim3(n2 + nD3, 1, B), blk, smemB, stream>>>(
            ref2, dist2, H2, W2, 0.0f, p2, sy2, sx2,
            ref2, dist2, ref3, dist3, H2, W2, H3, W3, 0.0f, dgx3, n2);
    }
    // K4: stats<3>(level3)
    stats_only_kernel<3><<<dim3(n3, 1, B), blk, stats_smem(3), stream>>>(
        ref3, dist3, H3, W3, 0.0f, p3, sy3, sx3);

    // K5: num/den per (b, scale)
    reduce_kernel<<<16, 256, 0, stream>>>(
        part, out,
        make_int4(0, B * n0, B * (n0 + n1), B * (n0 + n1 + n2)),
        make_int4(n0, n1, n2, n3));
}

// Round 6
// 254.761 us; speedup vs baseline: 1.4530x; 1.4530x over previous
//
#include <hip/hip_runtime.h>
#include <math.h>

#define VIF_EPS       1e-10f
#define SIGMA_NSQ     2.0f
#define SIGMA_MAX_INV (4.0f / (255.0f * 255.0f))
#define GAIN_LIMIT    100.0f

// jnp.pad mode='reflect' (no edge duplication). Overshoot < dim, single reflection suffices.
__device__ __forceinline__ int reflect_idx(int i, int n) {
    i = (i < 0) ? -i : i;
    i = (i >= n) ? (2 * n - 2 - i) : i;
    return i;
}

// Reference: sigma=N/5; g=exp(-x^2/(2 sigma^2)); win=outer(g,g)/sum -> separable gn = g/sum(g).
template <int N>
__device__ __forceinline__ void compute_weights(float* wts) {
    if (threadIdx.x == 0) {
        const float sigma = (float)N / 5.0f;
        const float denom = 2.0f * sigma * sigma;
        float s = 0.0f;
        for (int i = 0; i < N; ++i) {
            float x = (float)i - (float)(N - 1) * 0.5f;
            float g = expf(-(x * x) / denom);
            wts[i] = g;
            s += g;
        }
        for (int i = 0; i < N; ++i) wts[i] = wts[i] / s;
    }
}

// Output tile width (multiple of 4; phase 2 = 4 outputs/thread, round-4 proven VGPR=64).
constexpr int tile_w(int N) { return (128 - (N - 1)) & ~3; }

// ---- static shared layouts (16B-aligned members where float4 access happens) ----
template <int N>
struct StatsSmem {
    float v[5][8][132];   // offset 0; row stride 528 B = 33*16 -> float4-clean
    float wts[N];
    float rsum[8];
};
template <int N>
struct DownSmem {
    float lin[2][14 + N][(((62 + N) + 3) / 4) * 4];  // row stride multiple of 16 B
    float hd[2][14 + N][32];
    float wts[N];
};

// ---------------- stats body (vertical-first separable VIF, round-4 proven) ----------------
// bx flattened Y-MAJOR (ytile = bx % sy) so vertical-halo re-reads hit L2 from
// temporally adjacent blocks.
// Phase 1: 256 threads = 128 cols x 2 row-groups; coalesced global column loads,
//   5 product channels + N-tap vertical conv in registers (4 rows/thread); only
//   vertical results go to LDS: v[5][8][132].
// Phase 2: 4 consecutive x-outputs/thread (float4 register windows), N-tap horizontal
//   conv + VIF math, block reduction -> double2 partial.
// VGPR discipline: NO min-waves launch bound (R3: spill disaster), 4-wide phase 2
// (R5: 8-wide -> VGPR 96 -> occupancy collapse). Need >=8 waves/SIMD for phase-1 latency.
template <int N>
__device__ __forceinline__ void stats_body(
    StatsSmem<N>& sm, const float* __restrict__ refp, const float* __restrict__ distp,
    int h, int w, float shift, double2* __restrict__ partial,
    int sy, int sx, int bx, int b) {
    constexpr int P   = (N - 1) / 2;
    constexpr int VC  = 128;
    constexpr int TW  = tile_w(N);
    constexpr int TH  = 8;
    constexpr int Q   = 4;
    constexpr int LR  = Q + 2 * P;
    constexpr int VCP = 132;
    constexpr int XG  = TW / 4;
    constexpr int F4  = (N + 6) / 4;

    const int tid = threadIdx.x;
    const int ytile = bx % sy;
    const int xtile = bx / sy;
    const int x0 = xtile * TW;
    const int y0 = ytile * TH;

    compute_weights<N>(sm.wts);
    __syncthreads();

    float wr[N];
#pragma unroll
    for (int j = 0; j < N; ++j) wr[j] = sm.wts[j];

    // ---- Phase 1: vertical conv from global ----
    {
        const int c = tid & (VC - 1);
        const int g = tid >> 7;
        const int gx = reflect_idx(x0 + c - P, w);
        const float* rb = refp  + (size_t)b * h * w + gx;
        const float* db = distp + (size_t)b * h * w + gx;

        float acc[5][Q];
#pragma unroll
        for (int ch = 0; ch < 5; ++ch)
#pragma unroll
            for (int q = 0; q < Q; ++q) acc[ch][q] = 0.f;

#pragma unroll
        for (int i = 0; i < LR; ++i) {
            int gy = reflect_idx(y0 + g * Q - P + i, h);
            float r = rb[(size_t)gy * w] - shift;
            float d = db[(size_t)gy * w] - shift;
            float p0 = r, p1 = d, p2 = r * r, p3 = d * d, p4 = r * d;
#pragma unroll
            for (int q = 0; q < Q; ++q) {
                int j = i - q;
                if (j >= 0 && j < N) {
                    float wj = wr[j];
                    acc[0][q] += wj * p0;
                    acc[1][q] += wj * p1;
                    acc[2][q] += wj * p2;
                    acc[3][q] += wj * p3;
                    acc[4][q] += wj * p4;
                }
            }
        }
#pragma unroll
        for (int ch = 0; ch < 5; ++ch)
#pragma unroll
            for (int q = 0; q < Q; ++q)
                sm.v[ch][g * Q + q][c] = acc[ch][q];
    }
    __syncthreads();

    // ---- Phase 2: horizontal conv + VIF math (4 outputs/thread) ----
    float num_v = 0.f, den_v = 0.f;
    {
        const int xg  = tid & 31;
        const int row = tid >> 5;
        if (xg < XG) {
            float mu[5][4];
#pragma unroll
            for (int ch = 0; ch < 5; ++ch) {
                float win[F4 * 4];
                const float4* s4 = (const float4*)&sm.v[ch][row][xg * 4];
#pragma unroll
                for (int f = 0; f < F4; ++f) {
                    float4 t = s4[f];
                    win[4 * f + 0] = t.x; win[4 * f + 1] = t.y;
                    win[4 * f + 2] = t.z; win[4 * f + 3] = t.w;
                }
#pragma unroll
                for (int q = 0; q < 4; ++q) {
                    float a = 0.f;
#pragma unroll
                    for (int j = 0; j < N; ++j) a += wr[j] * win[q + j];
                    mu[ch][q] = a;
                }
            }
            const int gy = y0 + row;
#pragma unroll
            for (int q = 0; q < 4; ++q) {
                int gx = x0 + xg * 4 + q;
                if (gx < w && gy < h) {
                    float mu1 = mu[0][q], mu2 = mu[1][q];
                    float s1  = fmaxf(0.f, mu[2][q] - mu1 * mu1);
                    float s2  = fmaxf(0.f, mu[3][q] - mu2 * mu2);
                    float s12 = mu[4][q] - mu1 * mu2;

                    float g  = s12 / (s1 + VIF_EPS);
                    float sv = s2 - g * s12;
                    if (s1 < VIF_EPS) { g = 0.f; sv = s2; s1 = 0.f; }
                    if (s2 < VIF_EPS) { g = 0.f; sv = 0.f; }
                    if (g  < 0.f)     { sv = s2; g = 0.f; }
                    if (sv <= VIF_EPS) sv = VIF_EPS;
                    g = fminf(g, GAIN_LIMIT);

                    float num_ar = __log2f(1.f + g * g * s1 / (sv + SIGMA_NSQ));
                    float den_ar = __log2f(1.f + s1 / SIGMA_NSQ);
                    if (s12 < 0.f) num_ar = 0.f;
                    if (s1 < SIGMA_NSQ) { num_ar = 1.f - s2 * SIGMA_MAX_INV; den_ar = 1.f; }
                    num_v += num_ar;
                    den_v += den_ar;
                }
            }
        }
    }

    // Block reduction: wave shuffle then cross-wave via LDS.
#pragma unroll
    for (int off = 32; off > 0; off >>= 1) {
        num_v += __shfl_down(num_v, off);
        den_v += __shfl_down(den_v, off);
    }
    const int wid = tid >> 6, lane = tid & 63;
    if (lane == 0) { sm.rsum[wid] = num_v; sm.rsum[4 + wid] = den_v; }
    __syncthreads();
    if (tid == 0) {
        float ns = sm.rsum[0] + sm.rsum[1] + sm.rsum[2] + sm.rsum[3];
        float ds = sm.rsum[4] + sm.rsum[5] + sm.rsum[6] + sm.rsum[7];
        partial[(size_t)b * (sy * sx) + bx] = make_double2((double)ns, (double)ds);
    }
}

// ---------------- downsample body (separable stride-2, both images; round-4 proven) ----------------
template <int N>
__device__ __forceinline__ void down_body(
    DownSmem<N>& sm, const float* __restrict__ rin, const float* __restrict__ din,
    float* __restrict__ rout, float* __restrict__ dout,
    int h, int w, int h2, int w2, float shift, int dgx, int bx, int b) {
    constexpr int P   = (N - 1) / 2;
    constexpr int TOX = 32, TOY = 8;
    constexpr int IH  = 2 * (TOY - 1) + N;
    constexpr int IW  = 2 * (TOX - 1) + N;
    constexpr int IWP = ((IW + 3) / 4) * 4;
    constexpr int F4  = (N + 10) / 4;
    constexpr int NG  = 2 * IH * (TOX / 4);

    compute_weights<N>(sm.wts);

    const int tid = threadIdx.x;
    const int xt  = bx % dgx;
    const int yt  = bx / dgx;
    const int x0  = xt * TOX;
    const int y0  = yt * TOY;

    const float* src0 = rin + (size_t)b * h * w;
    const float* src1 = din + (size_t)b * h * w;

    __syncthreads();  // wts visible

    for (int idx = tid; idx < 2 * IH * IWP; idx += 256) {
        int img = idx / (IH * IWP);
        int rem = idx - img * IH * IWP;
        int r   = rem / IWP;
        int cx  = rem - r * IWP;
        int gy  = reflect_idx(2 * y0 - P + r, h);
        int gx  = reflect_idx(2 * x0 - P + cx, w);
        const float* src = img ? src1 : src0;
        (&sm.lin[0][0][0])[idx] = src[(size_t)gy * w + gx] - shift;
    }
    __syncthreads();

    for (int g = tid; g < NG; g += 256) {
        int img = g / (IH * 8);
        int rem = g - img * IH * 8;
        int r   = rem >> 3;
        int xg  = (rem & 7) * 4;
        float win[F4 * 4];
        const float4* src4 = (const float4*)&sm.lin[img][r][2 * xg];
#pragma unroll
        for (int f = 0; f < F4; ++f) {
            float4 t = src4[f];
            win[4 * f + 0] = t.x; win[4 * f + 1] = t.y;
            win[4 * f + 2] = t.z; win[4 * f + 3] = t.w;
        }
#pragma unroll
        for (int q = 0; q < 4; ++q) {
            float a = 0.f;
#pragma unroll
            for (int j = 0; j < N; ++j) a += sm.wts[j] * win[2 * q + j];
            sm.hd[img][r][xg + q] = a;
        }
    }
    __syncthreads();

    const int img = tid >> 7;
    const int rem = tid & 127;
    const int tx  = rem & 31;
    const int yg  = (rem >> 5) * 2;
    float* outp = (img ? dout : rout) + (size_t)b * h2 * w2;
#pragma unroll
    for (int q = 0; q < 2; ++q) {
        int yo = yg + q;
        int gy = y0 + yo, gx = x0 + tx;
        if (gy < h2 && gx < w2) {
            float a = 0.f;
#pragma unroll
            for (int j = 0; j < N; ++j) a += sm.wts[j] * sm.hd[img][2 * yo + j][tx];
            outp[(size_t)gy * w2 + gx] = a;
        }
    }
}

// ---------------- fused kernels (static union LDS; grid split by blockIdx.x) ----------------
// Blocks [0, nStats) run stats<NS> on level i; blocks [nStats, ...) run down<ND>
// producing level i+1. Independent tasks; down rides the stats tail waves.
template <int NS, int ND>
__global__ __launch_bounds__(256) void fused_kernel(
    const float* __restrict__ sref, const float* __restrict__ sdist,
    int sh, int sw, float sshift, double2* __restrict__ partial, int sy, int sx,
    float* __restrict__ drout, float* __restrict__ ddout,
    int dh2, int dw2, int dgx, int nStats) {
    __shared__ union {
        StatsSmem<NS> s;
        DownSmem<ND>  d;
    } u;
    const int bx = blockIdx.x;
    const int b  = blockIdx.z;
    if (bx < nStats)
        stats_body<NS>(u.s, sref, sdist, sh, sw, sshift, partial, sy, sx, bx, b);
    else
        down_body<ND>(u.d, sref, sdist, drout, ddout, sh, sw, dh2, dw2, sshift, dgx,
                      bx - nStats, b);
}

template <int N>
__global__ __launch_bounds__(256) void stats_only_kernel(
    const float* __restrict__ refp, const float* __restrict__ distp,
    int h, int w, float shift, double2* __restrict__ partial, int sy, int sx) {
    __shared__ StatsSmem<N> sm;
    stats_body<N>(sm, refp, distp, h, w, shift, partial, sy, sx, blockIdx.x, blockIdx.z);
}

// 16 blocks: one per (batch, scale). Sums double2 partials, writes num/den to out.
__global__ __launch_bounds__(256) void reduce_kernel(
    const double2* __restrict__ part, float* __restrict__ out,
    int4 bases, int4 counts) {
    __shared__ double sn[4], sd[4];
    const int s = blockIdx.x & 3;
    const int b = blockIdx.x >> 2;
    const int base = (&bases.x)[s];
    const int cnt  = (&counts.x)[s];
    const double2* p = part + base + (size_t)b * cnt;

    double ns = 0.0, ds = 0.0;
    for (int i = threadIdx.x; i < cnt; i += 256) {
        double2 v = p[i];
        ns += v.x;
        ds += v.y;
    }
#pragma unroll
    for (int off = 32; off > 0; off >>= 1) {
        ns += __shfl_down(ns, off);
        ds += __shfl_down(ds, off);
    }
    const int wid = threadIdx.x >> 6, lane = threadIdx.x & 63;
    if (lane == 0) { sn[wid] = ns; sd[wid] = ds; }
    __syncthreads();
    if (threadIdx.x == 0) {
        double Nv = sn[0] + sn[1] + sn[2] + sn[3];
        double Dv = sd[0] + sd[1] + sd[2] + sd[3];
        out[b * 4 + s] = (float)(Nv / Dv);
    }
}

extern "C" void kernel_launch(void* const* d_in, const int* in_sizes, int n_in,
                              void* d_out, int out_size, void* d_ws, size_t ws_size,
                              hipStream_t stream) {
    const float* ref  = (const float*)d_in[0];
    const float* dist = (const float*)d_in[1];
    float* out = (float*)d_out;

    const int B = 4;
    const int H0 = 1080, W0 = 1920;
    const int H1 = 540,  W1 = 960;
    const int H2 = 270,  W2 = 480;
    const int H3 = 135,  W3 = 240;

    char*  ws  = (char*)d_ws;
    size_t off = 0;
    auto alloc = [&](size_t bytes) -> void* {
        void* p = ws + off;
        off += (bytes + 255) & ~(size_t)255;
        return p;
    };
    float* ref1  = (float*)alloc((size_t)B * H1 * W1 * 4);
    float* dist1 = (float*)alloc((size_t)B * H1 * W1 * 4);
    float* ref2  = (float*)alloc((size_t)B * H2 * W2 * 4);
    float* dist2 = (float*)alloc((size_t)B * H2 * W2 * 4);
    float* ref3  = (float*)alloc((size_t)B * H3 * W3 * 4);
    float* dist3 = (float*)alloc((size_t)B * H3 * W3 * 4);

    // Stats grids (tile = tile_w(N) x 8), flattened y-major.
    const int sx0 = (W0 + tile_w(17) - 1) / tile_w(17), sy0 = (H0 + 7) / 8;
    const int sx1 = (W1 + tile_w(9)  - 1) / tile_w(9),  sy1 = (H1 + 7) / 8;
    const int sx2 = (W2 + tile_w(5)  - 1) / tile_w(5),  sy2 = (H2 + 7) / 8;
    const int sx3 = (W3 + tile_w(3)  - 1) / tile_w(3),  sy3 = (H3 + 7) / 8;
    const int n0 = sx0 * sy0, n1 = sx1 * sy1, n2 = sx2 * sy2, n3 = sx3 * sy3;

    // Down grids (32x8 output tiles), flattened x-fastest.
    const int dgx1 = (W1 + 31) / 32, nD1 = dgx1 * ((H1 + 7) / 8);
    const int dgx2 = (W2 + 31) / 32, nD2 = dgx2 * ((H2 + 7) / 8);
    const int dgx3 = (W3 + 31) / 32, nD3 = dgx3 * ((H3 + 7) / 8);

    double2* part = (double2*)alloc((size_t)B * (n0 + n1 + n2 + n3) * sizeof(double2));
    double2* p0 = part;
    double2* p1 = p0 + (size_t)B * n0;
    double2* p2 = p1 + (size_t)B * n1;
    double2* p3 = p2 + (size_t)B * n2;

    dim3 blk(256);

    // K1: stats<17>(level0) + down<9>(level0 -> level1). Shared input => L2/L3 reuse.
    fused_kernel<17, 9><<<dim3(n0 + nD1, 1, B), blk, 0, stream>>>(
        ref, dist, H0, W0, 128.0f, p0, sy0, sx0,
        ref1, dist1, H1, W1, dgx1, n0);

    // K2: stats<9>(level1) + down<5>(level1 -> level2)
    fused_kernel<9, 5><<<dim3(n1 + nD2, 1, B), blk, 0, stream>>>(
        ref1, dist1, H1, W1, 0.0f, p1, sy1, sx1,
        ref2, dist2, H2, W2, dgx2, n1);

    // K3: stats<5>(level2) + down<3>(level2 -> level3)
    fused_kernel<5, 3><<<dim3(n2 + nD3, 1, B), blk, 0, stream>>>(
        ref2, dist2, H2, W2, 0.0f, p2, sy2, sx2,
        ref3, dist3, H3, W3, dgx3, n2);

    // K4: stats<3>(level3)
    stats_only_kernel<3><<<dim3(n3, 1, B), blk, 0, stream>>>(
        ref3, dist3, H3, W3, 0.0f, p3, sy3, sx3);

    // K5: num/den per (b, scale)
    reduce_kernel<<<16, 256, 0, stream>>>(
        part, out,
        make_int4(0, B * n0, B * (n0 + n1), B * (n0 + n1 + n2)),
        make_int4(n0, n1, n2, n3));
}

// Round 7
// 214.705 us; speedup vs baseline: 1.7241x; 1.1866x over previous
//
#include <hip/hip_runtime.h>
#include <math.h>

#define VIF_EPS       1e-10f
#define SIGMA_NSQ     2.0f
#define SIGMA_MAX_INV (4.0f / (255.0f * 255.0f))
#define GAIN_LIMIT    100.0f

// jnp.pad mode='reflect' (no edge duplication). Overshoot < dim, single reflection suffices.
__device__ __forceinline__ int reflect_idx(int i, int n) {
    i = (i < 0) ? -i : i;
    i = (i >= n) ? (2 * n - 2 - i) : i;
    return i;
}

// Reference: sigma=N/5; g=exp(-x^2/(2 sigma^2)); win=outer(g,g)/sum -> separable gn = g/sum(g).
template <int N>
__device__ __forceinline__ void compute_weights(float* wts) {
    if (threadIdx.x == 0) {
        const float sigma = (float)N / 5.0f;
        const float denom = 2.0f * sigma * sigma;
        float s = 0.0f;
        for (int i = 0; i < N; ++i) {
            float x = (float)i - (float)(N - 1) * 0.5f;
            float g = expf(-(x * x) / denom);
            wts[i] = g;
            s += g;
        }
        for (int i = 0; i < N; ++i) wts[i] = wts[i] / s;
    }
}

// Output tile width (multiple of 4; phase 2 = 4 outputs/thread, round-4 proven VGPR=64).
constexpr int tile_w(int N) { return (128 - (N - 1)) & ~3; }

// ---- static shared layouts ----
template <int N>
struct StatsSmem {
    float v[5][8][132];   // row stride 528 B = 33*16 -> float4-clean
    float wts[N];
    float rsum[8];
};
// Down: vertical results for a 120x8 output tile (both images). 252-float row stride.
template <int N>
struct DownSmem {
    float vb[2][8][252];
    float wts[N];
};

// ---------------- stats body (vertical-first separable VIF) ----------------
// bx flattened Y-MAJOR (ytile = bx % sy) for L2 reuse of vertical halos.
// VGPR discipline: NO min-waves launch bound (R3: 930 MB spill), 4-wide phase 2
// (R5: 8-wide -> VGPR 96 -> occupancy collapse).
template <int N>
__device__ __forceinline__ void stats_body(
    StatsSmem<N>& sm, const float* __restrict__ refp, const float* __restrict__ distp,
    int h, int w, float shift, double2* __restrict__ partial,
    int sy, int sx, int bx, int b) {
    constexpr int P   = (N - 1) / 2;
    constexpr int VC  = 128;
    constexpr int TW  = tile_w(N);
    constexpr int TH  = 8;
    constexpr int Q   = 4;
    constexpr int LR  = Q + 2 * P;
    constexpr int XG  = TW / 4;
    constexpr int F4  = (N + 6) / 4;

    const int tid = threadIdx.x;
    const int ytile = bx % sy;
    const int xtile = bx / sy;
    const int x0 = xtile * TW;
    const int y0 = ytile * TH;

    compute_weights<N>(sm.wts);
    __syncthreads();

    float wr[N];
#pragma unroll
    for (int j = 0; j < N; ++j) wr[j] = sm.wts[j];

    // ---- Phase 1: vertical conv from global ----
    {
        const int c = tid & (VC - 1);
        const int g = tid >> 7;
        const int gx = reflect_idx(x0 + c - P, w);
        const float* rb = refp  + (size_t)b * h * w + gx;
        const float* db = distp + (size_t)b * h * w + gx;

        float acc[5][Q];
#pragma unroll
        for (int ch = 0; ch < 5; ++ch)
#pragma unroll
            for (int q = 0; q < Q; ++q) acc[ch][q] = 0.f;

        auto acc_push = [&](int i, float r, float d) {
            float p2 = r * r, p3 = d * d, p4 = r * d;
#pragma unroll
            for (int q = 0; q < Q; ++q) {
                int j = i - q;
                if (j >= 0 && j < N) {
                    float wj = wr[j];
                    acc[0][q] += wj * r;
                    acc[1][q] += wj * d;
                    acc[2][q] += wj * p2;
                    acc[3][q] += wj * p3;
                    acc[4][q] += wj * p4;
                }
            }
        };

        const int rowlo = y0 + g * Q - P;
        if (rowlo >= 0 && rowlo + LR <= h) {
            // Interior fast path (wave-uniform: g is constant per wave):
            // single pointer walk, no reflect / 64-bit mul per row.
            const float* pr = rb + (size_t)rowlo * w;
            const float* pd = db + (size_t)rowlo * w;
#pragma unroll
            for (int i = 0; i < LR; ++i) {
                float r = pr[0] - shift;
                float d = pd[0] - shift;
                pr += w; pd += w;
                acc_push(i, r, d);
            }
        } else {
#pragma unroll
            for (int i = 0; i < LR; ++i) {
                int gy = reflect_idx(rowlo + i, h);
                float r = rb[(size_t)gy * w] - shift;
                float d = db[(size_t)gy * w] - shift;
                acc_push(i, r, d);
            }
        }
#pragma unroll
        for (int ch = 0; ch < 5; ++ch)
#pragma unroll
            for (int q = 0; q < Q; ++q)
                sm.v[ch][g * Q + q][c] = acc[ch][q];
    }
    __syncthreads();

    // ---- Phase 2: horizontal conv + VIF math (4 outputs/thread) ----
    float num_v = 0.f, den_v = 0.f;
    {
        const int xg  = tid & 31;
        const int row = tid >> 5;
        if (xg < XG) {
            float mu[5][4];
#pragma unroll
            for (int ch = 0; ch < 5; ++ch) {
                float win[F4 * 4];
                const float4* s4 = (const float4*)&sm.v[ch][row][xg * 4];
#pragma unroll
                for (int f = 0; f < F4; ++f) {
                    float4 t = s4[f];
                    win[4 * f + 0] = t.x; win[4 * f + 1] = t.y;
                    win[4 * f + 2] = t.z; win[4 * f + 3] = t.w;
                }
#pragma unroll
                for (int q = 0; q < 4; ++q) {
                    float a = 0.f;
#pragma unroll
                    for (int j = 0; j < N; ++j) a += wr[j] * win[q + j];
                    mu[ch][q] = a;
                }
            }
            const int gy = y0 + row;
#pragma unroll
            for (int q = 0; q < 4; ++q) {
                int gx = x0 + xg * 4 + q;
                if (gx < w && gy < h) {
                    float mu1 = mu[0][q], mu2 = mu[1][q];
                    float s1  = fmaxf(0.f, mu[2][q] - mu1 * mu1);
                    float s2  = fmaxf(0.f, mu[3][q] - mu2 * mu2);
                    float s12 = mu[4][q] - mu1 * mu2;

                    float g  = s12 / (s1 + VIF_EPS);
                    float sv = s2 - g * s12;
                    if (s1 < VIF_EPS) { g = 0.f; sv = s2; s1 = 0.f; }
                    if (s2 < VIF_EPS) { g = 0.f; sv = 0.f; }
                    if (g  < 0.f)     { sv = s2; g = 0.f; }
                    if (sv <= VIF_EPS) sv = VIF_EPS;
                    g = fminf(g, GAIN_LIMIT);

                    float num_ar = __log2f(1.f + g * g * s1 / (sv + SIGMA_NSQ));
                    float den_ar = __log2f(1.f + s1 / SIGMA_NSQ);
                    if (s12 < 0.f) num_ar = 0.f;
                    if (s1 < SIGMA_NSQ) { num_ar = 1.f - s2 * SIGMA_MAX_INV; den_ar = 1.f; }
                    num_v += num_ar;
                    den_v += den_ar;
                }
            }
        }
    }

    // Block reduction.
#pragma unroll
    for (int off = 32; off > 0; off >>= 1) {
        num_v += __shfl_down(num_v, off);
        den_v += __shfl_down(den_v, off);
    }
    const int wid = tid >> 6, lane = tid & 63;
    if (lane == 0) { sm.rsum[wid] = num_v; sm.rsum[4 + wid] = den_v; }
    __syncthreads();
    if (tid == 0) {
        float ns = sm.rsum[0] + sm.rsum[1] + sm.rsum[2] + sm.rsum[3];
        float ds = sm.rsum[4] + sm.rsum[5] + sm.rsum[6] + sm.rsum[7];
        partial[(size_t)b * (sy * sx) + bx] = make_double2((double)ns, (double)ds);
    }
}

// ---------------- downsample body: vertical-first, 120x8 output tile ----------------
// Vert: thread = input column c in [0, 238+N); coalesced loads down the column
//   (interior fast path = pointer walk), 8 stride-2 N-tap outputs per image into
//   LDS vb[img][8][252]. Horiz: thread = (img,row,xg-of-8); float4 window reads,
//   8 stride-2 N-tap outputs, float4 global stores. Tile widths divide W exactly
//   (960/480/240 are multiples of 120) so no x store guard needed.
template <int N>
__device__ __forceinline__ void down_body(
    DownSmem<N>& sm, const float* __restrict__ rin, const float* __restrict__ din,
    float* __restrict__ rout, float* __restrict__ dout,
    int h, int w, int h2, int w2, float shift, int dgx, int bx, int b) {
    constexpr int P   = (N - 1) / 2;
    constexpr int TOW = 120, TOH = 8;
    constexpr int IC  = 2 * (TOW - 1) + N;   // input cols needed (<= 247)
    constexpr int NR  = 2 * (TOH - 1) + N;   // input rows needed (14+N)
    constexpr int XGn = TOW / 8;             // 15 x-groups
    constexpr int WL  = 14 + N;              // horiz window floats
    constexpr int F4n = (WL + 3) / 4;

    compute_weights<N>(sm.wts);
    __syncthreads();

    float wr[N];
#pragma unroll
    for (int j = 0; j < N; ++j) wr[j] = sm.wts[j];

    const int tid = threadIdx.x;
    const int xt  = bx % dgx;
    const int yt  = bx / dgx;
    const int x0  = xt * TOW;
    const int y0  = yt * TOH;

    // ---- Vertical decimating pass ----
    if (tid < IC) {
        const int gx = reflect_idx(2 * x0 - P + tid, w);
        const int rowlo = 2 * y0 - P;
        const bool interior = (rowlo >= 0) && (rowlo + NR <= h);
#pragma unroll
        for (int img = 0; img < 2; ++img) {
            const float* src = (img ? din : rin) + (size_t)b * h * w + gx;
            float rows[NR];
            if (interior) {
                const float* p = src + (size_t)rowlo * w;
#pragma unroll
                for (int i = 0; i < NR; ++i) { rows[i] = p[0] - shift; p += w; }
            } else {
#pragma unroll
                for (int i = 0; i < NR; ++i)
                    rows[i] = src[(size_t)reflect_idx(rowlo + i, h) * w] - shift;
            }
#pragma unroll
            for (int t = 0; t < TOH; ++t) {
                float a = 0.f;
#pragma unroll
                for (int j = 0; j < N; ++j) a += wr[j] * rows[2 * t + j];
                sm.vb[img][t][tid] = a;
            }
        }
    }
    __syncthreads();

    // ---- Horizontal decimating pass ----
    if (tid < 2 * TOH * XGn) {
        const int img = tid / (TOH * XGn);
        const int rem = tid - img * (TOH * XGn);
        const int row = rem / XGn;
        const int xg  = rem - row * XGn;

        float win[F4n * 4];
        const float4* s4 = (const float4*)&sm.vb[img][row][16 * xg];
#pragma unroll
        for (int f = 0; f < F4n; ++f) {
            float4 t = s4[f];
            win[4 * f + 0] = t.x; win[4 * f + 1] = t.y;
            win[4 * f + 2] = t.z; win[4 * f + 3] = t.w;
        }
        float o[8];
#pragma unroll
        for (int q = 0; q < 8; ++q) {
            float a = 0.f;
#pragma unroll
            for (int j = 0; j < N; ++j) a += wr[j] * win[2 * q + j];
            o[q] = a;
        }
        const int gy = y0 + row;
        if (gy < h2) {
            float* outp = (img ? dout : rout) + (size_t)b * h2 * w2
                        + (size_t)gy * w2 + x0 + 8 * xg;
            *(float4*)outp       = make_float4(o[0], o[1], o[2], o[3]);
            *(float4*)(outp + 4) = make_float4(o[4], o[5], o[6], o[7]);
        }
    }
}

// ---------------- fused kernels (static union LDS; grid split by blockIdx.x) ----------------
template <int NS, int ND>
__global__ __launch_bounds__(256) void fused_kernel(
    const float* __restrict__ sref, const float* __restrict__ sdist,
    int sh, int sw, float sshift, double2* __restrict__ partial, int sy, int sx,
    float* __restrict__ drout, float* __restrict__ ddout,
    int dh2, int dw2, int dgx, int nStats) {
    __shared__ union {
        StatsSmem<NS> s;
        DownSmem<ND>  d;
    } u;
    const int bx = blockIdx.x;
    const int b  = blockIdx.z;
    if (bx < nStats)
        stats_body<NS>(u.s, sref, sdist, sh, sw, sshift, partial, sy, sx, bx, b);
    else
        down_body<ND>(u.d, sref, sdist, drout, ddout, sh, sw, dh2, dw2, sshift, dgx,
                      bx - nStats, b);
}

template <int N>
__global__ __launch_bounds__(256) void stats_only_kernel(
    const float* __restrict__ refp, const float* __restrict__ distp,
    int h, int w, float shift, double2* __restrict__ partial, int sy, int sx) {
    __shared__ StatsSmem<N> sm;
    stats_body<N>(sm, refp, distp, h, w, shift, partial, sy, sx, blockIdx.x, blockIdx.z);
}

// 16 blocks: one per (batch, scale). Sums double2 partials, writes num/den to out.
__global__ __launch_bounds__(256) void reduce_kernel(
    const double2* __restrict__ part, float* __restrict__ out,
    int4 bases, int4 counts) {
    __shared__ double sn[4], sd[4];
    const int s = blockIdx.x & 3;
    const int b = blockIdx.x >> 2;
    const int base = (&bases.x)[s];
    const int cnt  = (&counts.x)[s];
    const double2* p = part + base + (size_t)b * cnt;

    double ns = 0.0, ds = 0.0;
    for (int i = threadIdx.x; i < cnt; i += 256) {
        double2 v = p[i];
        ns += v.x;
        ds += v.y;
    }
#pragma unroll
    for (int off = 32; off > 0; off >>= 1) {
        ns += __shfl_down(ns, off);
        ds += __shfl_down(ds, off);
    }
    const int wid = threadIdx.x >> 6, lane = threadIdx.x & 63;
    if (lane == 0) { sn[wid] = ns; sd[wid] = ds; }
    __syncthreads();
    if (threadIdx.x == 0) {
        double Nv = sn[0] + sn[1] + sn[2] + sn[3];
        double Dv = sd[0] + sd[1] + sd[2] + sd[3];
        out[b * 4 + s] = (float)(Nv / Dv);
    }
}

extern "C" void kernel_launch(void* const* d_in, const int* in_sizes, int n_in,
                              void* d_out, int out_size, void* d_ws, size_t ws_size,
                              hipStream_t stream) {
    const float* ref  = (const float*)d_in[0];
    const float* dist = (const float*)d_in[1];
    float* out = (float*)d_out;

    const int B = 4;
    const int H0 = 1080, W0 = 1920;
    const int H1 = 540,  W1 = 960;
    const int H2 = 270,  W2 = 480;
    const int H3 = 135,  W3 = 240;

    char*  ws  = (char*)d_ws;
    size_t off = 0;
    auto alloc = [&](size_t bytes) -> void* {
        void* p = ws + off;
        off += (bytes + 255) & ~(size_t)255;
        return p;
    };
    float* ref1  = (float*)alloc((size_t)B * H1 * W1 * 4);
    float* dist1 = (float*)alloc((size_t)B * H1 * W1 * 4);
    float* ref2  = (float*)alloc((size_t)B * H2 * W2 * 4);
    float* dist2 = (float*)alloc((size_t)B * H2 * W2 * 4);
    float* ref3  = (float*)alloc((size_t)B * H3 * W3 * 4);
    float* dist3 = (float*)alloc((size_t)B * H3 * W3 * 4);

    // Stats grids (tile = tile_w(N) x 8), flattened y-major.
    const int sx0 = (W0 + tile_w(17) - 1) / tile_w(17), sy0 = (H0 + 7) / 8;
    const int sx1 = (W1 + tile_w(9)  - 1) / tile_w(9),  sy1 = (H1 + 7) / 8;
    const int sx2 = (W2 + tile_w(5)  - 1) / tile_w(5),  sy2 = (H2 + 7) / 8;
    const int sx3 = (W3 + tile_w(3)  - 1) / tile_w(3),  sy3 = (H3 + 7) / 8;
    const int n0 = sx0 * sy0, n1 = sx1 * sy1, n2 = sx2 * sy2, n3 = sx3 * sy3;

    // Down grids: 120x8 output tiles (W1/W2/W3 are exact multiples of 120).
    const int dgx1 = W1 / 120, nD1 = dgx1 * ((H1 + 7) / 8);
    const int dgx2 = W2 / 120, nD2 = dgx2 * ((H2 + 7) / 8);
    const int dgx3 = W3 / 120, nD3 = dgx3 * ((H3 + 7) / 8);

    double2* part = (double2*)alloc((size_t)B * (n0 + n1 + n2 + n3) * sizeof(double2));
    double2* p0 = part;
    double2* p1 = p0 + (size_t)B * n0;
    double2* p2 = p1 + (size_t)B * n1;
    double2* p3 = p2 + (size_t)B * n2;

    dim3 blk(256);

    // K1: stats<17>(level0) + down<9>(level0 -> level1)
    fused_kernel<17, 9><<<dim3(n0 + nD1, 1, B), blk, 0, stream>>>(
        ref, dist, H0, W0, 128.0f, p0, sy0, sx0,
        ref1, dist1, H1, W1, dgx1, n0);

    // K2: stats<9>(level1) + down<5>(level1 -> level2)
    fused_kernel<9, 5><<<dim3(n1 + nD2, 1, B), blk, 0, stream>>>(
        ref1, dist1, H1, W1, 0.0f, p1, sy1, sx1,
        ref2, dist2, H2, W2, dgx2, n1);

    // K3: stats<5>(level2) + down<3>(level2 -> level3)
    fused_kernel<5, 3><<<dim3(n2 + nD3, 1, B), blk, 0, stream>>>(
        ref2, dist2, H2, W2, 0.0f, p2, sy2, sx2,
        ref3, dist3, H3, W3, dgx3, n2);

    // K4: stats<3>(level3)
    stats_only_kernel<3><<<dim3(n3, 1, B), blk, 0, stream>>>(
        ref3, dist3, H3, W3, 0.0f, p3, sy3, sx3);

    // K5: num/den per (b, scale)
    reduce_kernel<<<16, 256, 0, stream>>>(
        part, out,
        make_int4(0, B * n0, B * (n0 + n1), B * (n0 + n1 + n2)),
        make_int4(n0, n1, n2, n3));
}